// Round 11
// baseline (50.137 us; speedup 1.0000x reference)
//
#include <hip/hip_runtime.h>

// N=8, C=256, H=W=64, A=9, bs=8, F=8, K=64, M=A*N*K=4608
constexpr int N_ = 8, C_ = 256, H_ = 64, W_ = 64, A_ = 9, F_ = 8, K_ = 64;
constexpr int NPOS = 512;                  // N*F*F positions
constexpr int PSTRIDE = 9 * 32;            // per-position partials: [9 anchors][32 slices]
constexpr int NJOBS = A_ * N_ * (C_ / 8);  // 2304 fused jobs (one (a,n), 8 ch each)
#define ALPHA_BS 0.8f                      // ALPHA(0.1) * bs(8)
#define L2E 1.442695040888963f

typedef float f32x2 __attribute__((ext_vector_type(2)));

// ---------------------------------------------------------------------------
// kA: conv partials, W register-stationary. 2048 blocks = (pair, g, chunk):
// chunk = bi&7 == XCD id; g = (n,gy); pair picks 2 of 8 gx. Thread t =
// (cl=t>>3, r=t&7) holds W[a][c][r][0..7] in regs (18 float4). Per gx:
// 2 feat float4 loads, 72 FMA, 6-step butterfly (8 rows + wave's 8 channels)
// -> one scalar per (wave, a, gx) -> partials[p][a][chunk*4+wid]. 589 KB.
// ---------------------------------------------------------------------------
__global__ __launch_bounds__(256) void kA(const float* __restrict__ feat,
                                          const float* __restrict__ Wreg,
                                          float* __restrict__ partials) {
    const int bi = blockIdx.x;
    const int chunk = bi & 7;
    const int g = (bi >> 3) & 63;
    const int pair = bi >> 9;              // 0..3
    const int n = g >> 3, gy = g & 7;
    const int t = threadIdx.x;
    const int lane = t & 63, wid = t >> 6;
    const int r = t & 7;
    const int c = chunk * 32 + (t >> 3);

    const float* wp = Wreg + chunk * 2048 + t * 8;
    float4 w0[9], w1[9];
#pragma unroll
    for (int a = 0; a < 9; ++a) {
        w0[a] = *(const float4*)(wp + (size_t)a * 16384);
        w1[a] = *(const float4*)(wp + (size_t)a * 16384 + 4);
    }
    const float* frow = feat + (((size_t)n * C_ + c) * H_ + gy * 8 + r) * W_;
#pragma unroll
    for (int i = 0; i < 2; ++i) {
        const int gx = pair * 2 + i;
        const float4 f0 = *(const float4*)(frow + gx * 8);
        const float4 f1 = *(const float4*)(frow + gx * 8 + 4);
        float* pp = partials + (size_t)(g * 8 + gx) * PSTRIDE + chunk * 4 + wid;
#pragma unroll
        for (int a = 0; a < 9; ++a) {
            float s = f0.x * w0[a].x + f0.y * w0[a].y + f0.z * w0[a].z + f0.w * w0[a].w;
            s = fmaf(f1.x, w1[a].x, s);
            s = fmaf(f1.y, w1[a].y, s);
            s = fmaf(f1.z, w1[a].z, s);
            s = fmaf(f1.w, w1[a].w, s);
            s += __shfl_xor(s, 1, 64);     // rows (lane bits 0..2)
            s += __shfl_xor(s, 2, 64);
            s += __shfl_xor(s, 4, 64);
            s += __shfl_xor(s, 8, 64);     // the wave's 8 channels (bits 3..5)
            s += __shfl_xor(s, 16, 64);
            s += __shfl_xor(s, 32, 64);
            if (lane == 0) pp[a * 32] = s;
        }
    }
}

// ---------------------------------------------------------------------------
// kRfB: offsets + bilinear sample + both rois stages. 2304 blocks x 128 thr
// (2 waves). ILP probe: each wave owns 4 channels (c0=4w) as TWO independent
// f32x2 chains; one 16B-aligned ds_read_b128 per i feeds both ([64][12] rows:
// 48B stride keeps both quads 16B-aligned). If R8-R10's ~33us was
// dependent-chain latency, this doubles per-wave ILP -> ~20-24us; if the
// trans pipe is the floor, time is unchanged (diagnostic either way).
// ---------------------------------------------------------------------------
__global__ __launch_bounds__(128, 4) void kRfB(const float* __restrict__ rois_a,
                                               const float* __restrict__ feat,
                                               const float* __restrict__ partials,
                                               const float* __restrict__ breg,
                                               const float* __restrict__ rois_c,
                                               float* __restrict__ out) {
    __shared__ __align__(16) float sa[64][12];
    __shared__ __align__(16) float sb[64][12];
    __shared__ __align__(16) float sc[64][12];
    __shared__ float soff[64];

    const int bi = blockIdx.x;
    const int n  = bi & 7;                 // XCD-aligned image
    const int r9 = bi >> 3;                // 0..287
    const int a9 = r9 >> 5;                // anchor 0..8
    const int cb = (r9 & 31) * 8;          // channel base
    const int na = a9 * N_ + n;
    const int t = threadIdx.x, lane = t & 63, w = t >> 6;   // w in {0,1}
    const int c0 = 4 * w;                  // this wave's 4 channels
    const size_t base = (size_t)na * 64;

    // ---- offsets: thread (q=t&1, jj=t>>1) sums 16 of 32 partial slices ----
    {
        const int q = t & 1, jj = t >> 1;
        const float* pp = partials +
            (size_t)((n * 8 + (jj >> 3)) * 8 + (jj & 7)) * PSTRIDE + a9 * 32 + q * 16;
        float s = 0.f;
#pragma unroll
        for (int k = 0; k < 4; ++k) {
            const float4 v = *(const float4*)(pp + k * 4);
            s += v.x + v.y + v.z + v.w;
        }
        s += __shfl_xor(s, 1, 64);
        if (q == 0) soff[jj] = ALPHA_BS * tanhf(s + breg[a9]);
    }

    // ---- stage rois_a / prefetch rois_c (coalesced 32B segments) ----
    float rc[4];
#pragma unroll
    for (int k = 0; k < 4; ++k) {
        int idx = t + 128 * k;
        int i = idx >> 3, cc = idx & 7;
        sa[i][cc] = rois_a[(base + i) * 256 + cb + cc];
        rc[k]     = rois_c[(base + i) * 256 + cb + cc];
    }
    __syncthreads();

    // ---- bilinear sample -> sb: t = (j=t&63, cg=t>>6), 4 channels each ----
    {
        const int j = t & 63, cg = t >> 6;
        const int gy = j >> 3, gx = j & 7;
        const float off = soff[j];
        const float cx = 3.5f + 8.0f * gx + off;
        const float cy = 3.5f + 8.0f * gy + off;
        const float x0f = floorf(cx), y0f = floorf(cy);
        const float wx = cx - x0f, wy = cy - y0f;
        const int x0 = (int)x0f, y0 = (int)y0f;    // in [2,60]: clamps never fire
        const float w00 = (1.f - wx) * (1.f - wy), w01 = wx * (1.f - wy);
        const float w10 = (1.f - wx) * wy,         w11 = wx * wy;
#pragma unroll
        for (int k = 0; k < 4; ++k) {
            const int c = cb + cg * 4 + k;
            const float* fp = feat + (((size_t)n * C_ + c) * H_ + y0) * W_ + x0;
            const float v00 = fp[0], v01 = fp[1];
            const float v10 = fp[W_], v11 = fp[W_ + 1];
            sb[j][cg * 4 + k] = w00 * v00 + w01 * v01 + w10 * v10 + w11 * v11;
        }
    }
    __syncthreads();

    // ---- stage 1: a = rois_a (sa), b = sampled (sb), 2 chains/wave ----
    const float4 a4 = *(const float4*)&sa[lane][c0];
    const float4 b4 = *(const float4*)&sb[lane][c0];
    const f32x2 a1A = {a4.x, a4.y}, a1B = {a4.z, a4.w};
    const f32x2 b1A = {b4.x, b4.y}, b1B = {b4.z, b4.w};
    f32x2 o1A, o1B;
    {
        float mxA0 = a1A.x, mnA0 = a1A.x, mxA1 = a1A.y, mnA1 = a1A.y;
        float mxB0 = a1B.x, mnB0 = a1B.x, mxB1 = a1B.y, mnB1 = a1B.y;
#pragma unroll
        for (int s = 32; s; s >>= 1) {
            mxA0 = fmaxf(mxA0, __shfl_xor(mxA0, s, 64));
            mnA0 = fminf(mnA0, __shfl_xor(mnA0, s, 64));
            mxA1 = fmaxf(mxA1, __shfl_xor(mxA1, s, 64));
            mnA1 = fminf(mnA1, __shfl_xor(mnA1, s, 64));
            mxB0 = fmaxf(mxB0, __shfl_xor(mxB0, s, 64));
            mnB0 = fminf(mnB0, __shfl_xor(mnB0, s, 64));
            mxB1 = fmaxf(mxB1, __shfl_xor(mxB1, s, 64));
            mnB1 = fminf(mnB1, __shfl_xor(mnB1, s, 64));
        }
        f32x2 mA, mB;
        mA.x = b1A.x > 0.f ? b1A.x * mxA0 : b1A.x * mnA0;
        mA.y = b1A.y > 0.f ? b1A.y * mxA1 : b1A.y * mnA1;
        mB.x = b1B.x > 0.f ? b1B.x * mxB0 : b1B.x * mnB0;
        mB.y = b1B.y > 0.f ? b1B.y * mxB1 : b1B.y * mnB1;
        const f32x2 blA = b1A * L2E, blB = b1B * L2E;
        const f32x2 mlA = -mA * L2E,  mlB = -mB * L2E;
        f32x2 denA = {0.f, 0.f}, numA = {0.f, 0.f};
        f32x2 denB = {0.f, 0.f}, numB = {0.f, 0.f};
#pragma unroll 8
        for (int i = 0; i < 64; ++i) {
            const float4 av4 = *(const float4*)&sa[i][c0];   // uniform b128
            const f32x2 avA = {av4.x, av4.y}, avB = {av4.z, av4.w};
            f32x2 egA = avA * blA + mlA;
            f32x2 egB = avB * blB + mlB;
            f32x2 eA, eB;
            eA.x = __builtin_amdgcn_exp2f(egA.x);
            eA.y = __builtin_amdgcn_exp2f(egA.y);
            eB.x = __builtin_amdgcn_exp2f(egB.x);
            eB.y = __builtin_amdgcn_exp2f(egB.y);
            denA += eA; numA += eA * avA;
            denB += eB; numB += eB * avB;
        }
        o1A = b1A + numA / denA;
        o1B = b1B + numB / denB;
    }
    __syncthreads();            // all waves done reading sa/sb

    // re-stage: sa <- o1 (for i-broadcast), sb <- rois_c
    *(f32x2*)&sa[lane][c0]     = o1A;
    *(f32x2*)&sa[lane][c0 + 2] = o1B;
#pragma unroll
    for (int k = 0; k < 4; ++k) {
        int idx = t + 128 * k;
        sb[idx >> 3][idx & 7] = rc[k];
    }
    __syncthreads();

    // ---- stage 2: a = o1 (sa), b = rois_c (sb) ----
    {
        const float4 c4 = *(const float4*)&sb[lane][c0];
        const f32x2 b2A = {c4.x, c4.y}, b2B = {c4.z, c4.w};
        float mxA0 = o1A.x, mnA0 = o1A.x, mxA1 = o1A.y, mnA1 = o1A.y;
        float mxB0 = o1B.x, mnB0 = o1B.x, mxB1 = o1B.y, mnB1 = o1B.y;
#pragma unroll
        for (int s = 32; s; s >>= 1) {
            mxA0 = fmaxf(mxA0, __shfl_xor(mxA0, s, 64));
            mnA0 = fminf(mnA0, __shfl_xor(mnA0, s, 64));
            mxA1 = fmaxf(mxA1, __shfl_xor(mxA1, s, 64));
            mnA1 = fminf(mnA1, __shfl_xor(mnA1, s, 64));
            mxB0 = fmaxf(mxB0, __shfl_xor(mxB0, s, 64));
            mnB0 = fminf(mnB0, __shfl_xor(mnB0, s, 64));
            mxB1 = fmaxf(mxB1, __shfl_xor(mxB1, s, 64));
            mnB1 = fminf(mnB1, __shfl_xor(mnB1, s, 64));
        }
        f32x2 mA, mB;
        mA.x = b2A.x > 0.f ? b2A.x * mxA0 : b2A.x * mnA0;
        mA.y = b2A.y > 0.f ? b2A.y * mxA1 : b2A.y * mnA1;
        mB.x = b2B.x > 0.f ? b2B.x * mxB0 : b2B.x * mnB0;
        mB.y = b2B.y > 0.f ? b2B.y * mxB1 : b2B.y * mnB1;
        const f32x2 blA = b2A * L2E, blB = b2B * L2E;
        const f32x2 mlA = -mA * L2E,  mlB = -mB * L2E;
        f32x2 denA = {0.f, 0.f}, numA = {0.f, 0.f};
        f32x2 denB = {0.f, 0.f}, numB = {0.f, 0.f};
#pragma unroll 8
        for (int i = 0; i < 64; ++i) {
            const float4 av4 = *(const float4*)&sa[i][c0];   // uniform b128
            const f32x2 avA = {av4.x, av4.y}, avB = {av4.z, av4.w};
            f32x2 egA = avA * blA + mlA;
            f32x2 egB = avB * blB + mlB;
            f32x2 eA, eB;
            eA.x = __builtin_amdgcn_exp2f(egA.x);
            eA.y = __builtin_amdgcn_exp2f(egA.y);
            eB.x = __builtin_amdgcn_exp2f(egB.x);
            eB.y = __builtin_amdgcn_exp2f(egB.y);
            denA += eA; numA += eA * avA;
            denB += eB; numB += eB * avB;
        }
        *(f32x2*)&sc[lane][c0]     = b2A + numA / denA;
        *(f32x2*)&sc[lane][c0 + 2] = b2B + numB / denB;
    }
    __syncthreads();

    // ---- coalesced writeback ----
#pragma unroll
    for (int k = 0; k < 4; ++k) {
        int idx = t + 128 * k;
        int i = idx >> 3, cc = idx & 7;
        out[(base + i) * 256 + cb + cc] = sc[i][cc];
    }
}

// ---------------------------------------------------------------------------
extern "C" void kernel_launch(void* const* d_in, const int* in_sizes, int n_in,
                              void* d_out, int out_size, void* d_ws, size_t ws_size,
                              hipStream_t stream) {
    // inputs: ori_feature_shape, rois_feature_a, feature_b, rois_feature_c, W_reg, b_reg
    const float* rois_a = (const float*)d_in[1];
    const float* feat   = (const float*)d_in[2];
    const float* rois_c = (const float*)d_in[3];
    const float* Wreg   = (const float*)d_in[4];
    const float* breg   = (const float*)d_in[5];
    float* out = (float*)d_out;
    float* partials = (float*)d_ws;        // 512*288 floats = 589 KB

    kA<<<dim3(NPOS * 4), dim3(256), 0, stream>>>(feat, Wreg, partials);
    kRfB<<<dim3(NJOBS), dim3(128), 0, stream>>>(rois_a, feat, partials, breg,
                                                rois_c, out);
}